// Round 10
// baseline (278.697 us; speedup 1.0000x reference)
//
#include <hip/hip_runtime.h>
#include <hip/hip_fp16.h>

#define NN 50000
#define NP 50176     // padded node count (196*256)
#define FF 256
#define EE 1000000
#define MM 2
#define CAP 64

#define NB 196       // coarse bins: dst>>8
#define CAPBIN 6144
#define ACHUNK 4096
#define ABLK 245     // ceil(EE/ACHUNK)

typedef __attribute__((ext_vector_type(8))) short bf16x8;
typedef __attribute__((ext_vector_type(4))) float f32x4;
typedef _Float16 h2_t __attribute__((ext_vector_type(2)));

__device__ inline unsigned short f2bf(float f) {
  union { float f; unsigned u; } v; v.f = f;
  unsigned r = (v.u + 0x7FFF + ((v.u >> 16) & 1)) >> 16;
  return (unsigned short)r;
}

__device__ inline float2 u32_to_f2(unsigned int u) {
  union { unsigned int u; __half2 h; } c; c.u = u;
  return __half22float2(c.h);
}

__device__ inline h2_t as_h2(unsigned int u) {
  union { unsigned int u; h2_t h; } c; c.u = u;
  return c.h;
}

#if __has_builtin(__builtin_amdgcn_fdot2)
__device__ inline float dot2acc(h2_t w, unsigned int h, float acc) {
  return __builtin_amdgcn_fdot2(w, as_h2(h), acc, false);
}
#else
__device__ inline float dot2acc(h2_t w, unsigned int h, float acc) {
  float2 hf = u32_to_f2(h);
  acc = fmaf((float)w[0], hf.x, acc);
  return fmaf((float)w[1], hf.y, acc);
}
#endif

// ---------------- fused front: edge coarse-binning | Wt cast | beta + xbf ----------------
#define PARTA_BLKS (2 * ABLK)   // 490
#define WT_BLKS 256
#define BETA_BLKS 12500
__global__ __launch_bounds__(256) void k_front(const int* __restrict__ e0,
                                               const int* __restrict__ e1,
                                               int* __restrict__ cursor,
                                               uint2* __restrict__ binned,
                                               const float* __restrict__ W,
                                               unsigned short* __restrict__ Wt,
                                               const float* __restrict__ x,
                                               const float* __restrict__ cw,
                                               const float* __restrict__ cb,
                                               float* __restrict__ beta,
                                               unsigned short* __restrict__ xbf) {
  __shared__ int lsrc[ACHUNK];
  __shared__ int ldst[ACHUNK];
  __shared__ int cnt[NB], base[NB], pos[NB];
  int b = blockIdx.x;
  int tid = threadIdx.x;
  if (b < PARTA_BLKS) {
    int m = (b >= ABLK) ? 1 : 0;
    int ab = b - m * ABLK;
    const int* e = m ? e1 : e0;
    int j0 = ab * ACHUNK;
    int nj = min(ACHUNK, EE - j0);
    if (tid < NB) { cnt[tid] = 0; pos[tid] = 0; }
    __syncthreads();
    for (int i = tid; i < nj; i += 256) {
      int s = e[j0 + i], d = e[EE + j0 + i];
      lsrc[i] = s; ldst[i] = d;
      atomicAdd(&cnt[d >> 8], 1);
    }
    __syncthreads();
    if (tid < NB) {
      base[tid] = (cnt[tid] > 0) ? atomicAdd(&cursor[m * NB + tid], cnt[tid]) : 0;
    }
    __syncthreads();
    for (int i = tid; i < nj; i += 256) {
      int d = ldst[i], bin = d >> 8;
      int lp = atomicAdd(&pos[bin], 1);
      int slot = base[bin] + lp;
      if (slot < CAPBIN)
        binned[((size_t)m * NB + bin) * CAPBIN + slot] =
            make_uint2((unsigned)lsrc[i], (unsigned)d);
    }
    return;
  }
  b -= PARTA_BLKS;
  if (b < WT_BLKS) {
    Wt[b * 256 + tid] = f2bf(W[tid * 256 + b]);
    return;
  }
  b -= WT_BLKS;
  {
    int wid  = b * 4 + (tid >> 6);
    int lane = tid & 63;
    float4 xv = *reinterpret_cast<const float4*>(x + (size_t)wid * FF + lane * 4);
    union { unsigned short s[4]; unsigned long long u; } pk;
    pk.s[0] = f2bf(xv.x); pk.s[1] = f2bf(xv.y); pk.s[2] = f2bf(xv.z); pk.s[3] = f2bf(xv.w);
    *((unsigned long long*)(xbf + (size_t)wid * FF) + lane) = pk.u;
    float s[3];
#pragma unroll
    for (int r = 0; r < 3; ++r) {
      float4 wv = *reinterpret_cast<const float4*>(cw + r * FF + lane * 4);
      float p = xv.x * wv.x + xv.y * wv.y + xv.z * wv.z + xv.w * wv.w;
#pragma unroll
      for (int o = 1; o < 64; o <<= 1) p += __shfl_xor(p, o);
      s[r] = p + cb[r];
    }
    float mx = fmaxf(s[0], fmaxf(s[1], s[2]));
    float e0v = expf(s[0] - mx), e1v = expf(s[1] - mx), e2v = expf(s[2] - mx);
    float inv = 1.f / (e0v + e1v + e2v);
    if (lane == 0) {
      beta[wid * 3 + 0] = e0v * inv;
      beta[wid * 3 + 1] = e1v * inv;
      beta[wid * 3 + 2] = e2v * inv;
    }
  }
}

// ---------------- MFMA GEMM -> h16t (transposed) + al[m][n][hh] ----------------
__global__ __launch_bounds__(256) void k_gemm(const unsigned short* __restrict__ xbf,
                                              const unsigned short* __restrict__ Wt,
                                              const float* __restrict__ bias,
                                              const float* __restrict__ attn_l,
                                              unsigned short* __restrict__ h16t,
                                              float* __restrict__ al) {
  __shared__ unsigned short Asm[64 * 40];
  __shared__ unsigned short Bsm[64 * 40];
  __shared__ unsigned short Ht[64 * 64];
  const int t = threadIdx.x;
  const int lane = t & 63, w = t >> 6;
  const int wm = (w & 1) * 32, wn = (w >> 1) * 32;
  const int hh = blockIdx.y;
  const int r0 = blockIdx.x * 64, c0 = hh * 64;
  const int srow = t >> 2, skoff = (t & 3) * 8;

  f32x4 acc[2][2] = {};
  const int arow = lane & 15, kg = (lane >> 4) * 8;

  for (int k0 = 0; k0 < FF; k0 += 32) {
    int gr = r0 + srow; if (gr >= NN) gr = NN - 1;
    *(uint4*)&Asm[srow * 40 + skoff] =
        *(const uint4*)(xbf + (size_t)gr * FF + k0 + skoff);
    *(uint4*)&Bsm[srow * 40 + skoff] =
        *(const uint4*)(Wt + (size_t)(c0 + srow) * FF + k0 + skoff);
    __syncthreads();
    bf16x8 afr[2], bfr[2];
    afr[0] = *(bf16x8*)&Asm[(wm + arow) * 40 + kg];
    afr[1] = *(bf16x8*)&Asm[(wm + 16 + arow) * 40 + kg];
    bfr[0] = *(bf16x8*)&Bsm[(wn + arow) * 40 + kg];
    bfr[1] = *(bf16x8*)&Bsm[(wn + 16 + arow) * 40 + kg];
#pragma unroll
    for (int mi = 0; mi < 2; ++mi)
#pragma unroll
      for (int ni = 0; ni < 2; ++ni)
        acc[mi][ni] = __builtin_amdgcn_mfma_f32_16x16x32_bf16(afr[mi], bfr[ni],
                                                              acc[mi][ni], 0, 0, 0);
    __syncthreads();
  }

#pragma unroll
  for (int mi = 0; mi < 2; ++mi)
#pragma unroll
    for (int ni = 0; ni < 2; ++ni) {
      int col = wn + ni * 16 + (lane & 15);
      float bv = bias[c0 + col];
#pragma unroll
      for (int r = 0; r < 4; ++r) {
        int row = wm + mi * 16 + (lane >> 4) * 4 + r;
        Ht[row * 64 + col] = __half_as_ushort(__float2half(acc[mi][ni][r] + bv));
      }
    }
  __syncthreads();
  {
    int row = t >> 2, q = t & 3;
    int gr = r0 + row;
    // al[m][gr][hh] = sum_d Ht[row][d] * attn_l[m][hh][d]
    float pa0 = 0.f, pa1 = 0.f;
#pragma unroll
    for (int dq = 0; dq < 16; ++dq) {
      int d = q * 16 + dq;
      float hv = __half2float(__ushort_as_half(Ht[row * 64 + d]));
      pa0 = fmaf(hv, attn_l[0 * 256 + hh * 64 + d], pa0);
      pa1 = fmaf(hv, attn_l[1 * 256 + hh * 64 + d], pa1);
    }
    pa0 += __shfl_xor(pa0, 1); pa0 += __shfl_xor(pa0, 2);
    pa1 += __shfl_xor(pa1, 1); pa1 += __shfl_xor(pa1, 2);
    if (gr < NN) {
      if (q == 0) {
        al[((size_t)0 * NP + gr) * 4 + hh] = pa0;
        al[((size_t)1 * NP + gr) * 4 + hh] = pa1;
      }
      // h16t scatter: h16t[gr][d*4 + hh] = Ht[row][d]
      unsigned short* dst = h16t + (size_t)gr * 256 + hh;
#pragma unroll
      for (int dq = 0; dq < 16; ++dq) {
        int d = q * 16 + dq;
        dst[d * 4] = Ht[row * 64 + d];
      }
    }
  }
}

// ---------------- fused back: partb (bin -> CAP buckets) | eal pack ----------------
#define PARTB_BLKS (2 * NB)  // 392
#define EAL_BLKS NB          // 196 * 256 = 50176 >= NN
__global__ __launch_bounds__(256) void k_back(const int* __restrict__ cursor,
                                              const uint2* __restrict__ binned,
                                              int* __restrict__ off,
                                              int* __restrict__ rec,
                                              const float* __restrict__ al,
                                              const float* __restrict__ alpha,
                                              unsigned long long* __restrict__ eal) {
  __shared__ int cnt[256], pos[256];
  int b = blockIdx.x;
  int tid = threadIdx.x;
  if (b < PARTB_BLKS) {
    int m = (b >= NB) ? 1 : 0;
    int bin = b - m * NB;
    int n = min(cursor[m * NB + bin], CAPBIN);
    cnt[tid] = 0; pos[tid] = 0;
    __syncthreads();
    const uint2* seg = binned + ((size_t)m * NB + bin) * CAPBIN;
    for (int i = tid; i < n; i += 256) atomicAdd(&cnt[seg[i].y & 255], 1);
    __syncthreads();
    int dg = bin * 256 + tid;
    if (dg < NN) off[(size_t)m * NN + dg] = min(cnt[tid], CAP);
    for (int i = tid; i < n; i += 256) {
      uint2 r = seg[i];
      int dl = (int)(r.y & 255u);
      int lp = atomicAdd(&pos[dl], 1);
      if (lp < CAP) rec[((size_t)m * NN + r.y) * CAP + lp] = (int)r.x;
    }
    return;
  }
  b -= PARTB_BLKS;
  {
    int n = b * 256 + tid;
    if (n >= NN) return;
    float a0 = alpha[0], a1 = alpha[1];
    float4 v0 = *reinterpret_cast<const float4*>(al + ((size_t)0 * NP + n) * 4);
    float4 v1 = *reinterpret_cast<const float4*>(al + ((size_t)1 * NP + n) * 4);
    union { unsigned short s[4]; unsigned long long u; } p0, p1;
    p0.s[0] = __half_as_ushort(__float2half(__expf(a0 * v0.x)));
    p0.s[1] = __half_as_ushort(__float2half(__expf(a0 * v0.y)));
    p0.s[2] = __half_as_ushort(__float2half(__expf(a0 * v0.z)));
    p0.s[3] = __half_as_ushort(__float2half(__expf(a0 * v0.w)));
    p1.s[0] = __half_as_ushort(__float2half(__expf(a1 * v1.x)));
    p1.s[1] = __half_as_ushort(__float2half(__expf(a1 * v1.y)));
    p1.s[2] = __half_as_ushort(__float2half(__expf(a1 * v1.z)));
    p1.s[3] = __half_as_ushort(__float2half(__expf(a1 * v1.w)));
    eal[(size_t)0 * NN + n] = p0.u;
    eal[(size_t)1 * NN + n] = p1.u;
  }
}

// ---------------- aggregate: one wave per dst; softmax-normalize in-register ----------------
__global__ __launch_bounds__(256) void k_agg(const int* __restrict__ off,
                                             const int* __restrict__ rec,
                                             const unsigned long long* __restrict__ eal,
                                             const __half* __restrict__ h16t,
                                             const float* __restrict__ beta,
                                             float* __restrict__ out) {
  int lane = threadIdx.x & 63;
  int dst  = (int)((blockIdx.x * (size_t)blockDim.x + threadIdx.x) >> 6);
  if (dst >= NN) return;
  int dstu = __builtin_amdgcn_readfirstlane(dst);
  const unsigned long long* h64 = (const unsigned long long*)h16t;
  float msg = 0.f;
#pragma unroll
  for (int m = 0; m < MM; ++m) {
    int cntm = off[(size_t)m * NN + dstu];
    cntm = min(cntm, CAP);
    if (cntm <= 0) continue;
    const int* rr = rec + ((size_t)m * NN + dstu) * CAP;
    int srcl = 0;
    unsigned int el = 0, eh = 0;
    float s0 = 0.f, s1 = 0.f, s2 = 0.f, s3 = 0.f;
    if (lane < cntm) {
      srcl = rr[lane];
      unsigned long long ev = eal[(size_t)m * NN + srcl];
      el = (unsigned int)ev; eh = (unsigned int)(ev >> 32);
      float2 w01 = u32_to_f2(el), w23 = u32_to_f2(eh);
      s0 = w01.x; s1 = w01.y; s2 = w23.x; s3 = w23.y;
    }
#pragma unroll
    for (int o = 1; o < 64; o <<= 1) {
      s0 += __shfl_xor(s0, o);
      s1 += __shfl_xor(s1, o);
      s2 += __shfl_xor(s2, o);
      s3 += __shfl_xor(s3, o);
    }
    float bs = beta[dstu * 3 + m] * 0.25f;
    h2_t c01, c23;
    c01[0] = (_Float16)(bs / (s0 + 1e-16f));
    c01[1] = (_Float16)(bs / (s1 + 1e-16f));
    c23[0] = (_Float16)(bs / (s2 + 1e-16f));
    c23[1] = (_Float16)(bs / (s3 + 1e-16f));
    int p = 0;
    for (; p + 2 <= cntm; p += 2) {
      int sp0 = __shfl(srcl, p), sp1 = __shfl(srcl, p + 1);
      unsigned int wl0 = (unsigned int)__shfl((int)el, p);
      unsigned int wh0 = (unsigned int)__shfl((int)eh, p);
      unsigned int wl1 = (unsigned int)__shfl((int)el, p + 1);
      unsigned int wh1 = (unsigned int)__shfl((int)eh, p + 1);
      unsigned long long h0 = h64[(size_t)sp0 * 64 + lane];
      unsigned long long h1 = h64[(size_t)sp1 * 64 + lane];
      msg = dot2acc(as_h2(wl0) * c01, (unsigned int)(h0 & 0xFFFFFFFFu), msg);
      msg = dot2acc(as_h2(wh0) * c23, (unsigned int)(h0 >> 32), msg);
      msg = dot2acc(as_h2(wl1) * c01, (unsigned int)(h1 & 0xFFFFFFFFu), msg);
      msg = dot2acc(as_h2(wh1) * c23, (unsigned int)(h1 >> 32), msg);
    }
    if (p < cntm) {
      int sp0 = __shfl(srcl, p);
      unsigned int wl0 = (unsigned int)__shfl((int)el, p);
      unsigned int wh0 = (unsigned int)__shfl((int)eh, p);
      unsigned long long h0 = h64[(size_t)sp0 * 64 + lane];
      msg = dot2acc(as_h2(wl0) * c01, (unsigned int)(h0 & 0xFFFFFFFFu), msg);
      msg = dot2acc(as_h2(wh0) * c23, (unsigned int)(h0 >> 32), msg);
    }
  }
  // self-relation
  unsigned long long hs = h64[(size_t)dstu * 64 + lane];
  float2 h01 = u32_to_f2((unsigned int)(hs & 0xFFFFFFFFu));
  float2 h23 = u32_to_f2((unsigned int)(hs >> 32));
  float self = 0.25f * (h01.x + h01.y + h23.x + h23.y);
  float v = msg + beta[dstu * 3 + 2] * self;
  out[(size_t)dstu * 64 + lane] = fmaxf(v, 0.f);
}

extern "C" void kernel_launch(void* const* d_in, const int* in_sizes, int n_in,
                              void* d_out, int out_size, void* d_ws, size_t ws_size,
                              hipStream_t stream) {
  const float* x      = (const float*)d_in[0];
  const float* W      = (const float*)d_in[1];
  const float* b      = (const float*)d_in[2];
  const float* cw     = (const float*)d_in[3];
  const float* cb     = (const float*)d_in[4];
  const float* attn_l = (const float*)d_in[5];
  const float* attn_r = (const float*)d_in[6];  // unused: softmax shift-invariance cancels ar
  const float* alpha  = (const float*)d_in[7];
  const int*   e0     = (const int*)d_in[8];
  const int*   e1     = (const int*)d_in[9];
  float* out = (float*)d_out;
  (void)attn_r;

  char* p = (char*)d_ws;
  unsigned short* xbf  = (unsigned short*)p;  p += (size_t)NN * 256 * 2;        // 25.6 MB
  unsigned short* Wt   = (unsigned short*)p;  p += (size_t)256 * 256 * 2;       // 128 KB
  unsigned short* h16t = (unsigned short*)p;  p += (size_t)NN * 256 * 2;        // 25.6 MB
  uint2* binned = (uint2*)p;                  p += (size_t)MM * NB * CAPBIN * 8; // 19.3 MB
  float* al     = (float*)p;                  p += (size_t)MM * NP * 4 * 4;     // 1.6 MB
  unsigned long long* eal = (unsigned long long*)p; p += (size_t)MM * NN * 8;   // 800 KB
  float* beta   = (float*)p;                  p += (size_t)NN * 3 * 4;          // 600 KB
  int*   off    = (int*)p;                    p += (size_t)MM * NN * 4;         // 400 KB
  int*   rec    = (int*)p;                    p += (size_t)MM * NN * CAP * 4;   // 25.6 MB
  int*   cursor = (int*)p;                    p += (size_t)MM * NB * 4;         // 1.6 KB

  hipMemsetAsync(cursor, 0, (size_t)MM * NB * 4, stream);

  int frontBlocks = PARTA_BLKS + WT_BLKS + BETA_BLKS;
  k_front<<<frontBlocks, 256, 0, stream>>>(e0, e1, cursor, binned,
                                           W, Wt, x, cw, cb, beta, xbf);

  dim3 gg((NN + 63) / 64, 4);
  k_gemm<<<gg, 256, 0, stream>>>(xbf, Wt, b, attn_l, h16t, al);

  k_back<<<PARTB_BLKS + EAL_BLKS, 256, 0, stream>>>(cursor, binned, off, rec,
                                                    al, alpha, eal);

  int nodeBlocks = (NN * 64 + 255) / 256;  // 12500 blocks = 50000 waves
  k_agg<<<nodeBlocks, 256, 0, stream>>>(off, rec, eal, (const __half*)h16t, beta, out);
}

// Round 11
// 223.284 us; speedup vs baseline: 1.2482x; 1.2482x over previous
//
#include <hip/hip_runtime.h>
#include <hip/hip_fp16.h>

#define NN 50000
#define FF 256
#define EE 1000000
#define MM 2
#define CAP 64

#define NB 196       // coarse bins: dst>>8
#define CAPBIN 6144
#define ACHUNK 4096
#define ABLK 245     // ceil(EE/ACHUNK)

typedef __attribute__((ext_vector_type(8))) short bf16x8;
typedef __attribute__((ext_vector_type(4))) float f32x4;
typedef _Float16 h2_t __attribute__((ext_vector_type(2)));

__device__ inline unsigned short f2bf(float f) {
  union { float f; unsigned u; } v; v.f = f;
  unsigned r = (v.u + 0x7FFF + ((v.u >> 16) & 1)) >> 16;
  return (unsigned short)r;
}

__device__ inline float2 u32_to_f2(unsigned int u) {
  union { unsigned int u; __half2 h; } c; c.u = u;
  return __half22float2(c.h);
}

__device__ inline h2_t as_h2(unsigned int u) {
  union { unsigned int u; h2_t h; } c; c.u = u;
  return c.h;
}

#if __has_builtin(__builtin_amdgcn_fdot2)
__device__ inline float dot2acc(h2_t w, unsigned int h, float acc) {
  return __builtin_amdgcn_fdot2(w, as_h2(h), acc, false);
}
#else
__device__ inline float dot2acc(h2_t w, unsigned int h, float acc) {
  float2 hf = u32_to_f2(h);
  acc = fmaf((float)w[0], hf.x, acc);
  return fmaf((float)w[1], hf.y, acc);
}
#endif

// ---------------- fused front: edge coarse-binning | Wt cast | beta + xbf ----------------
#define PARTA_BLKS (2 * ABLK)   // 490
#define WT_BLKS 256
#define BETA_BLKS 12500
__global__ __launch_bounds__(256) void k_front(const int* __restrict__ e0,
                                               const int* __restrict__ e1,
                                               int* __restrict__ cursor,
                                               uint2* __restrict__ binned,
                                               const float* __restrict__ W,
                                               unsigned short* __restrict__ Wt,
                                               const float* __restrict__ x,
                                               const float* __restrict__ cw,
                                               const float* __restrict__ cb,
                                               float* __restrict__ beta,
                                               unsigned short* __restrict__ xbf) {
  __shared__ int lsrc[ACHUNK];
  __shared__ int ldst[ACHUNK];
  __shared__ int cnt[NB], base[NB], pos[NB];
  int b = blockIdx.x;
  int tid = threadIdx.x;
  if (b < PARTA_BLKS) {
    int m = (b >= ABLK) ? 1 : 0;
    int ab = b - m * ABLK;
    const int* e = m ? e1 : e0;
    int j0 = ab * ACHUNK;
    int nj = min(ACHUNK, EE - j0);
    if (tid < NB) { cnt[tid] = 0; pos[tid] = 0; }
    __syncthreads();
    for (int i = tid; i < nj; i += 256) {
      int s = e[j0 + i], d = e[EE + j0 + i];
      lsrc[i] = s; ldst[i] = d;
      atomicAdd(&cnt[d >> 8], 1);
    }
    __syncthreads();
    if (tid < NB) {
      base[tid] = (cnt[tid] > 0) ? atomicAdd(&cursor[m * NB + tid], cnt[tid]) : 0;
    }
    __syncthreads();
    for (int i = tid; i < nj; i += 256) {
      int d = ldst[i], bin = d >> 8;
      int lp = atomicAdd(&pos[bin], 1);
      int slot = base[bin] + lp;
      if (slot < CAPBIN)
        binned[((size_t)m * NB + bin) * CAPBIN + slot] =
            make_uint2((unsigned)lsrc[i], (unsigned)d);
    }
    return;
  }
  b -= PARTA_BLKS;
  if (b < WT_BLKS) {
    Wt[b * 256 + tid] = f2bf(W[tid * 256 + b]);
    return;
  }
  b -= WT_BLKS;
  {
    int wid  = b * 4 + (tid >> 6);
    int lane = tid & 63;
    float4 xv = *reinterpret_cast<const float4*>(x + (size_t)wid * FF + lane * 4);
    union { unsigned short s[4]; unsigned long long u; } pk;
    pk.s[0] = f2bf(xv.x); pk.s[1] = f2bf(xv.y); pk.s[2] = f2bf(xv.z); pk.s[3] = f2bf(xv.w);
    *((unsigned long long*)(xbf + (size_t)wid * FF) + lane) = pk.u;
    float s[3];
#pragma unroll
    for (int r = 0; r < 3; ++r) {
      float4 wv = *reinterpret_cast<const float4*>(cw + r * FF + lane * 4);
      float p = xv.x * wv.x + xv.y * wv.y + xv.z * wv.z + xv.w * wv.w;
#pragma unroll
      for (int o = 1; o < 64; o <<= 1) p += __shfl_xor(p, o);
      s[r] = p + cb[r];
    }
    float mx = fmaxf(s[0], fmaxf(s[1], s[2]));
    float e0v = expf(s[0] - mx), e1v = expf(s[1] - mx), e2v = expf(s[2] - mx);
    float inv = 1.f / (e0v + e1v + e2v);
    if (lane == 0) {
      beta[wid * 3 + 0] = e0v * inv;
      beta[wid * 3 + 1] = e1v * inv;
      beta[wid * 3 + 2] = e2v * inv;
    }
  }
}

// ---------------- fused: partb (bin->CAP buckets) | MFMA GEMM -> h16t + eal ----------------
// gemm: BM=32 x BN=256 full-width tiles, transposed-in-LDS epilogue, coalesced stores
#define PARTB_BLKS (2 * NB)          // 392
#define GB 1563                       // ceil(NN/32)
__global__ __launch_bounds__(256) void k_gemmb(const int* __restrict__ cursor,
                                               const uint2* __restrict__ binned,
                                               int* __restrict__ off,
                                               int* __restrict__ rec,
                                               const unsigned short* __restrict__ xbf,
                                               const unsigned short* __restrict__ Wt,
                                               const float* __restrict__ bias,
                                               const float* __restrict__ attn_l,
                                               const float* __restrict__ alpha,
                                               unsigned short* __restrict__ h16t,
                                               unsigned long long* __restrict__ eal) {
  __shared__ __attribute__((aligned(16))) char smem[(32 * 264 + 256 * 40) * 2];
  int b = blockIdx.x;
  int t = threadIdx.x;

  if (b < PARTB_BLKS) {
    int* cnt = (int*)smem;
    int* pos = cnt + 256;
    int m = (b >= NB) ? 1 : 0;
    int bin = b - m * NB;
    int n = min(cursor[m * NB + bin], CAPBIN);
    cnt[t] = 0; pos[t] = 0;
    __syncthreads();
    const uint2* seg = binned + ((size_t)m * NB + bin) * CAPBIN;
    for (int i = t; i < n; i += 256) atomicAdd(&cnt[seg[i].y & 255], 1);
    __syncthreads();
    int dg = bin * 256 + t;
    if (dg < NN) off[(size_t)m * NN + dg] = min(cnt[t], CAP);
    for (int i = t; i < n; i += 256) {
      uint2 r = seg[i];
      int dl = (int)(r.y & 255u);
      int lp = atomicAdd(&pos[dl], 1);
      if (lp < CAP) rec[((size_t)m * NN + r.y) * CAP + lp] = (int)r.x;
    }
    return;
  }
  b -= PARTB_BLKS;
  {
    unsigned short* As = (unsigned short*)smem;            // [32][264]
    unsigned short* Bs = As + 32 * 264;                    // [256][40]
    unsigned short* Htt = Bs;                              // reuse after K-loop: [32][264]
    const int lane = t & 63, w = t >> 6;
    const int wn = w * 64;
    const int r0 = b * 32;
    const int arow = lane & 15, kg = (lane >> 4) * 8;

    // stage A fully (32 rows x 256 k)
    {
      int row = t >> 3, kc = (t & 7) * 32;
      int gr = r0 + row; if (gr >= NN) gr = NN - 1;
      const unsigned short* sp = xbf + (size_t)gr * FF + kc;
      unsigned short* dp = As + row * 264 + kc;
#pragma unroll
      for (int q = 0; q < 4; ++q)
        *(uint4*)(dp + q * 8) = *(const uint4*)(sp + q * 8);
    }

    f32x4 acc[2][4] = {};
    for (int k0 = 0; k0 < FF; k0 += 32) {
      // stage B: all 256 Wt rows x 32 k
#pragma unroll
      for (int s = 0; s < 4; ++s) {
        int i = t + 256 * s;
        int n2 = i >> 2, ch = (i & 3) * 8;
        *(uint4*)(Bs + n2 * 40 + ch) = *(const uint4*)(Wt + (size_t)n2 * FF + k0 + ch);
      }
      __syncthreads();
      bf16x8 afr[2], bfr[4];
      afr[0] = *(bf16x8*)(As + arow * 264 + k0 + kg);
      afr[1] = *(bf16x8*)(As + (16 + arow) * 264 + k0 + kg);
#pragma unroll
      for (int ci = 0; ci < 4; ++ci)
        bfr[ci] = *(bf16x8*)(Bs + (wn + ci * 16 + arow) * 40 + kg);
#pragma unroll
      for (int mi = 0; mi < 2; ++mi)
#pragma unroll
        for (int ci = 0; ci < 4; ++ci)
          acc[mi][ci] = __builtin_amdgcn_mfma_f32_16x16x32_bf16(afr[mi], bfr[ci],
                                                                acc[mi][ci], 0, 0, 0);
      __syncthreads();
    }

    // epilogue: bias + fp16, write TRANSPOSED into LDS (tcol = d*4+hh)
#pragma unroll
    for (int mi = 0; mi < 2; ++mi)
#pragma unroll
      for (int ci = 0; ci < 4; ++ci) {
        int col = wn + ci * 16 + (lane & 15);
        int tcol = ((col & 63) << 2) | (col >> 6);
        float bv = bias[col];
#pragma unroll
        for (int r = 0; r < 4; ++r) {
          int row = mi * 16 + (lane >> 4) * 4 + r;
          Htt[row * 264 + tcol] = __half_as_ushort(__float2half(acc[mi][ci][r] + bv));
        }
      }
    __syncthreads();

    // coalesced h16t store + fused al/eal
    int row = t >> 3, c = t & 7;
    int gr = r0 + row;
    float pa[2][4] = {{0.f, 0.f, 0.f, 0.f}, {0.f, 0.f, 0.f, 0.f}};
    if (gr < NN) {
      uint4 v[4];
#pragma unroll
      for (int q = 0; q < 4; ++q)
        v[q] = *(uint4*)(Htt + row * 264 + c * 32 + q * 8);
      uint4* dst = (uint4*)(h16t + (size_t)gr * FF + c * 32);
#pragma unroll
      for (int q = 0; q < 4; ++q) dst[q] = v[q];
#pragma unroll
      for (int q = 0; q < 4; ++q) {
        const unsigned short* pv = (const unsigned short*)&v[q];
#pragma unroll
        for (int e = 0; e < 8; ++e) {
          int oo = q * 8 + e;
          int hh = oo & 3;
          int d  = c * 8 + (oo >> 2);
          float hv = __half2float(__ushort_as_half(pv[e]));
          pa[0][hh] = fmaf(hv, attn_l[hh * 64 + d], pa[0][hh]);
          pa[1][hh] = fmaf(hv, attn_l[256 + hh * 64 + d], pa[1][hh]);
        }
      }
    }
#pragma unroll
    for (int o = 1; o < 8; o <<= 1)
#pragma unroll
      for (int m2 = 0; m2 < 2; ++m2)
#pragma unroll
        for (int hh = 0; hh < 4; ++hh)
          pa[m2][hh] += __shfl_xor(pa[m2][hh], o);
    if (c == 0 && gr < NN) {
      float a0s = alpha[0], a1s = alpha[1];
      union { unsigned short s[4]; unsigned long long u; } p0, p1;
#pragma unroll
      for (int hh = 0; hh < 4; ++hh) {
        p0.s[hh] = __half_as_ushort(__float2half(__expf(a0s * pa[0][hh])));
        p1.s[hh] = __half_as_ushort(__float2half(__expf(a1s * pa[1][hh])));
      }
      eal[gr] = p0.u;
      eal[(size_t)NN + gr] = p1.u;
    }
  }
}

// ---------------- aggregate: one wave per dst; softmax-normalize in-register ----------------
__global__ __launch_bounds__(256) void k_agg(const int* __restrict__ off,
                                             const int* __restrict__ rec,
                                             const unsigned long long* __restrict__ eal,
                                             const __half* __restrict__ h16t,
                                             const float* __restrict__ beta,
                                             float* __restrict__ out) {
  int lane = threadIdx.x & 63;
  int dst  = (int)((blockIdx.x * (size_t)blockDim.x + threadIdx.x) >> 6);
  if (dst >= NN) return;
  int dstu = __builtin_amdgcn_readfirstlane(dst);
  const unsigned long long* h64 = (const unsigned long long*)h16t;
  float msg = 0.f;
#pragma unroll
  for (int m = 0; m < MM; ++m) {
    int cntm = off[(size_t)m * NN + dstu];
    cntm = min(cntm, CAP);
    if (cntm <= 0) continue;
    const int* rr = rec + ((size_t)m * NN + dstu) * CAP;
    int srcl = 0;
    unsigned int el = 0, eh = 0;
    float s0 = 0.f, s1 = 0.f, s2 = 0.f, s3 = 0.f;
    if (lane < cntm) {
      srcl = rr[lane];
      unsigned long long ev = eal[(size_t)m * NN + srcl];
      el = (unsigned int)ev; eh = (unsigned int)(ev >> 32);
      float2 w01 = u32_to_f2(el), w23 = u32_to_f2(eh);
      s0 = w01.x; s1 = w01.y; s2 = w23.x; s3 = w23.y;
    }
#pragma unroll
    for (int o = 1; o < 64; o <<= 1) {
      s0 += __shfl_xor(s0, o);
      s1 += __shfl_xor(s1, o);
      s2 += __shfl_xor(s2, o);
      s3 += __shfl_xor(s3, o);
    }
    float bs = beta[dstu * 3 + m] * 0.25f;
    h2_t c01, c23;
    c01[0] = (_Float16)(bs / (s0 + 1e-16f));
    c01[1] = (_Float16)(bs / (s1 + 1e-16f));
    c23[0] = (_Float16)(bs / (s2 + 1e-16f));
    c23[1] = (_Float16)(bs / (s3 + 1e-16f));
    int p = 0;
    for (; p + 2 <= cntm; p += 2) {
      int sp0 = __shfl(srcl, p), sp1 = __shfl(srcl, p + 1);
      unsigned int wl0 = (unsigned int)__shfl((int)el, p);
      unsigned int wh0 = (unsigned int)__shfl((int)eh, p);
      unsigned int wl1 = (unsigned int)__shfl((int)el, p + 1);
      unsigned int wh1 = (unsigned int)__shfl((int)eh, p + 1);
      unsigned long long h0 = h64[(size_t)sp0 * 64 + lane];
      unsigned long long h1 = h64[(size_t)sp1 * 64 + lane];
      msg = dot2acc(as_h2(wl0) * c01, (unsigned int)(h0 & 0xFFFFFFFFu), msg);
      msg = dot2acc(as_h2(wh0) * c23, (unsigned int)(h0 >> 32), msg);
      msg = dot2acc(as_h2(wl1) * c01, (unsigned int)(h1 & 0xFFFFFFFFu), msg);
      msg = dot2acc(as_h2(wh1) * c23, (unsigned int)(h1 >> 32), msg);
    }
    if (p < cntm) {
      int sp0 = __shfl(srcl, p);
      unsigned int wl0 = (unsigned int)__shfl((int)el, p);
      unsigned int wh0 = (unsigned int)__shfl((int)eh, p);
      unsigned long long h0 = h64[(size_t)sp0 * 64 + lane];
      msg = dot2acc(as_h2(wl0) * c01, (unsigned int)(h0 & 0xFFFFFFFFu), msg);
      msg = dot2acc(as_h2(wh0) * c23, (unsigned int)(h0 >> 32), msg);
    }
  }
  // self-relation
  unsigned long long hs = h64[(size_t)dstu * 64 + lane];
  float2 h01 = u32_to_f2((unsigned int)(hs & 0xFFFFFFFFu));
  float2 h23 = u32_to_f2((unsigned int)(hs >> 32));
  float self = 0.25f * (h01.x + h01.y + h23.x + h23.y);
  float v = msg + beta[dstu * 3 + 2] * self;
  out[(size_t)dstu * 64 + lane] = fmaxf(v, 0.f);
}

extern "C" void kernel_launch(void* const* d_in, const int* in_sizes, int n_in,
                              void* d_out, int out_size, void* d_ws, size_t ws_size,
                              hipStream_t stream) {
  const float* x      = (const float*)d_in[0];
  const float* W      = (const float*)d_in[1];
  const float* b      = (const float*)d_in[2];
  const float* cw     = (const float*)d_in[3];
  const float* cb     = (const float*)d_in[4];
  const float* attn_l = (const float*)d_in[5];
  const float* attn_r = (const float*)d_in[6];  // unused: softmax shift-invariance cancels ar
  const float* alpha  = (const float*)d_in[7];
  const int*   e0     = (const int*)d_in[8];
  const int*   e1     = (const int*)d_in[9];
  float* out = (float*)d_out;
  (void)attn_r;

  char* p = (char*)d_ws;
  unsigned short* xbf  = (unsigned short*)p;  p += (size_t)NN * 256 * 2;         // 25.6 MB
  unsigned short* Wt   = (unsigned short*)p;  p += (size_t)256 * 256 * 2;        // 128 KB
  unsigned short* h16t = (unsigned short*)p;  p += (size_t)NN * 256 * 2;         // 25.6 MB
  uint2* binned = (uint2*)p;                  p += (size_t)MM * NB * CAPBIN * 8; // 19.3 MB
  unsigned long long* eal = (unsigned long long*)p; p += (size_t)MM * NN * 8;    // 800 KB
  float* beta   = (float*)p;                  p += (size_t)NN * 3 * 4;           // 600 KB
  int*   off    = (int*)p;                    p += (size_t)MM * NN * 4;          // 400 KB
  int*   rec    = (int*)p;                    p += (size_t)MM * NN * CAP * 4;    // 25.6 MB
  int*   cursor = (int*)p;                    p += (size_t)MM * NB * 4;          // 1.6 KB

  hipMemsetAsync(cursor, 0, (size_t)MM * NB * 4, stream);

  int frontBlocks = PARTA_BLKS + WT_BLKS + BETA_BLKS;
  k_front<<<frontBlocks, 256, 0, stream>>>(e0, e1, cursor, binned,
                                           W, Wt, x, cw, cb, beta, xbf);

  k_gemmb<<<PARTB_BLKS + GB, 256, 0, stream>>>(cursor, binned, off, rec,
                                               xbf, Wt, b, attn_l, alpha, h16t, eal);

  int nodeBlocks = (NN * 64 + 255) / 256;  // 12500 blocks = 50000 waves
  k_agg<<<nodeBlocks, 256, 0, stream>>>(off, rec, eal, (const __half*)h16t, beta, out);
}

// Round 13
// 219.384 us; speedup vs baseline: 1.2704x; 1.0178x over previous
//
#include <hip/hip_runtime.h>
#include <hip/hip_fp16.h>
#include <hip/hip_fp8.h>

#define NN 50000
#define FF 256
#define EE 1000000
#define MM 2
#define CAP 64

#define NB 196       // coarse bins: dst>>8
#define CAPBIN 6144
#define ACHUNK 4096
#define ABLK 245     // ceil(EE/ACHUNK)

typedef __attribute__((ext_vector_type(8))) short bf16x8;
typedef __attribute__((ext_vector_type(4))) float f32x4;
typedef __attribute__((ext_vector_type(2))) float f32x2;

__device__ inline unsigned short f2bf(float f) {
  union { float f; unsigned u; } v; v.f = f;
  unsigned r = (v.u + 0x7FFF + ((v.u >> 16) & 1)) >> 16;
  return (unsigned short)r;
}

__device__ inline float2 u32_to_f2(unsigned int u) {
  union { unsigned int u; __half2 h; } c; c.u = u;
  return __half22float2(c.h);
}

#if __has_builtin(__builtin_amdgcn_cvt_pk_f32_fp8) && __has_builtin(__builtin_amdgcn_cvt_pk_fp8_f32)
template <bool HI>
__device__ inline float2 fp8pair_to_f2(unsigned int u) {
  f32x2 r = __builtin_amdgcn_cvt_pk_f32_fp8((int)u, HI);
  return make_float2(r[0], r[1]);
}
template <bool HI>
__device__ inline unsigned int f2_to_fp8pair(float a, float b, unsigned int old) {
  return (unsigned int)__builtin_amdgcn_cvt_pk_fp8_f32(a, b, (int)old, HI);
}
#else
template <bool HI>
__device__ inline float2 fp8pair_to_f2(unsigned int u) {
  unsigned int w = HI ? (u >> 16) : (u & 0xFFFFu);
  __half_raw h0 = __hip_cvt_fp8_to_halfraw((__hip_fp8_storage_t)(w & 0xFF), __HIP_E4M3);
  __half_raw h1 = __hip_cvt_fp8_to_halfraw((__hip_fp8_storage_t)(w >> 8), __HIP_E4M3);
  return make_float2(__half2float(__half(h0)), __half2float(__half(h1)));
}
template <bool HI>
__device__ inline unsigned int f2_to_fp8pair(float a, float b, unsigned int old) {
  unsigned int pa = (unsigned int)__hip_cvt_float_to_fp8(a, __HIP_SATFINITE, __HIP_E4M3);
  unsigned int pb = (unsigned int)__hip_cvt_float_to_fp8(b, __HIP_SATFINITE, __HIP_E4M3);
  unsigned int w = pa | (pb << 8);
  return HI ? ((old & 0x0000FFFFu) | (w << 16)) : ((old & 0xFFFF0000u) | w);
}
#endif

// ---------------- fused front: edge coarse-binning | Wt cast | beta ----------------
#define PARTA_BLKS (2 * ABLK)   // 490
#define WT_BLKS 256
#define BETA_BLKS 12500
__global__ __launch_bounds__(256) void k_front(const int* __restrict__ e0,
                                               const int* __restrict__ e1,
                                               int* __restrict__ cursor,
                                               uint2* __restrict__ binned,
                                               const float* __restrict__ W,
                                               unsigned short* __restrict__ Wt,
                                               const float* __restrict__ x,
                                               const float* __restrict__ cw,
                                               const float* __restrict__ cb,
                                               float* __restrict__ beta) {
  __shared__ int lsrc[ACHUNK];
  __shared__ int ldst[ACHUNK];
  __shared__ int cnt[NB], base[NB], pos[NB];
  int b = blockIdx.x;
  int tid = threadIdx.x;
  if (b < PARTA_BLKS) {
    int m = (b >= ABLK) ? 1 : 0;
    int ab = b - m * ABLK;
    const int* e = m ? e1 : e0;
    int j0 = ab * ACHUNK;
    int nj = min(ACHUNK, EE - j0);
    if (tid < NB) { cnt[tid] = 0; pos[tid] = 0; }
    __syncthreads();
    for (int i = tid; i < nj; i += 256) {
      int s = e[j0 + i], d = e[EE + j0 + i];
      lsrc[i] = s; ldst[i] = d;
      atomicAdd(&cnt[d >> 8], 1);
    }
    __syncthreads();
    if (tid < NB) {
      base[tid] = (cnt[tid] > 0) ? atomicAdd(&cursor[m * NB + tid], cnt[tid]) : 0;
    }
    __syncthreads();
    for (int i = tid; i < nj; i += 256) {
      int d = ldst[i], bin = d >> 8;
      int lp = atomicAdd(&pos[bin], 1);
      int slot = base[bin] + lp;
      if (slot < CAPBIN)
        binned[((size_t)m * NB + bin) * CAPBIN + slot] =
            make_uint2((unsigned)lsrc[i], (unsigned)d);
    }
    return;
  }
  b -= PARTA_BLKS;
  if (b < WT_BLKS) {
    Wt[b * 256 + tid] = f2bf(W[tid * 256 + b]);
    return;
  }
  b -= WT_BLKS;
  {
    int wid  = b * 4 + (tid >> 6);
    int lane = tid & 63;
    float4 xv = *reinterpret_cast<const float4*>(x + (size_t)wid * FF + lane * 4);
    float s[3];
#pragma unroll
    for (int r = 0; r < 3; ++r) {
      float4 wv = *reinterpret_cast<const float4*>(cw + r * FF + lane * 4);
      float p = xv.x * wv.x + xv.y * wv.y + xv.z * wv.z + xv.w * wv.w;
#pragma unroll
      for (int o = 1; o < 64; o <<= 1) p += __shfl_xor(p, o);
      s[r] = p + cb[r];
    }
    float mx = fmaxf(s[0], fmaxf(s[1], s[2]));
    float e0v = expf(s[0] - mx), e1v = expf(s[1] - mx), e2v = expf(s[2] - mx);
    float inv = 1.f / (e0v + e1v + e2v);
    if (lane == 0) {
      beta[wid * 3 + 0] = e0v * inv;
      beta[wid * 3 + 1] = e1v * inv;
      beta[wid * 3 + 2] = e2v * inv;
    }
  }
}

// ---------------- fused: partb | MFMA GEMM -> h8t (fp8, transposed) + eal + outbase ----------------
#define PARTB_BLKS (2 * NB)          // 392
#define GB 1563                       // ceil(NN/32)
__global__ __launch_bounds__(256) void k_gemmb(const int* __restrict__ cursor,
                                               const uint2* __restrict__ binned,
                                               int* __restrict__ off,
                                               int* __restrict__ rec,
                                               const float* __restrict__ x,
                                               const unsigned short* __restrict__ Wt,
                                               const float* __restrict__ bias,
                                               const float* __restrict__ attn_l,
                                               const float* __restrict__ alpha,
                                               const float* __restrict__ beta,
                                               unsigned int* __restrict__ h8t,
                                               float* __restrict__ outbase,
                                               unsigned long long* __restrict__ eal) {
  __shared__ __attribute__((aligned(16))) char smem[(32 * 264 + 256 * 40) * 2];
  int b = blockIdx.x;
  int t = threadIdx.x;

  if (b < PARTB_BLKS) {
    int* cnt = (int*)smem;
    int* pos = cnt + 256;
    int m = (b >= NB) ? 1 : 0;
    int bin = b - m * NB;
    int n = min(cursor[m * NB + bin], CAPBIN);
    cnt[t] = 0; pos[t] = 0;
    __syncthreads();
    const uint2* seg = binned + ((size_t)m * NB + bin) * CAPBIN;
    for (int i = t; i < n; i += 256) atomicAdd(&cnt[seg[i].y & 255], 1);
    __syncthreads();
    int dg = bin * 256 + t;
    if (dg < NN) off[(size_t)m * NN + dg] = min(cnt[t], CAP);
    for (int i = t; i < n; i += 256) {
      uint2 r = seg[i];
      int dl = (int)(r.y & 255u);
      int lp = atomicAdd(&pos[dl], 1);
      if (lp < CAP) rec[((size_t)m * NN + r.y) * CAP + lp] = (int)r.x;
    }
    return;
  }
  b -= PARTB_BLKS;
  {
    unsigned short* As = (unsigned short*)smem;            // [32][264]
    unsigned short* Bs = As + 32 * 264;                    // [256][40]
    unsigned short* Htt = Bs;                              // reuse after K-loop: [32][264]
    const int lane = t & 63, w = t >> 6;
    const int wn = w * 64;
    const int r0 = b * 32;
    const int arow = lane & 15, kg = (lane >> 4) * 8;

    // stage A fully (32 rows x 256 k) from fp32 x, cast to bf16
    {
      int row = t >> 3, kc = (t & 7) * 32;
      int gr = r0 + row; if (gr >= NN) gr = NN - 1;
      const float* sp = x + (size_t)gr * FF + kc;
      unsigned short* dp = As + row * 264 + kc;
#pragma unroll
      for (int q = 0; q < 8; ++q) {
        float4 f = *(const float4*)(sp + q * 4);
        unsigned short u[4] = {f2bf(f.x), f2bf(f.y), f2bf(f.z), f2bf(f.w)};
        *(uint2*)(dp + q * 4) = *(uint2*)u;
      }
    }

    f32x4 acc[2][4] = {};
    for (int k0 = 0; k0 < FF; k0 += 32) {
#pragma unroll
      for (int s = 0; s < 4; ++s) {
        int i = t + 256 * s;
        int n2 = i >> 2, ch = (i & 3) * 8;
        *(uint4*)(Bs + n2 * 40 + ch) = *(const uint4*)(Wt + (size_t)n2 * FF + k0 + ch);
      }
      __syncthreads();
      bf16x8 afr[2], bfr[4];
      afr[0] = *(bf16x8*)(As + arow * 264 + k0 + kg);
      afr[1] = *(bf16x8*)(As + (16 + arow) * 264 + k0 + kg);
#pragma unroll
      for (int ci = 0; ci < 4; ++ci)
        bfr[ci] = *(bf16x8*)(Bs + (wn + ci * 16 + arow) * 40 + kg);
#pragma unroll
      for (int mi = 0; mi < 2; ++mi)
#pragma unroll
        for (int ci = 0; ci < 4; ++ci)
          acc[mi][ci] = __builtin_amdgcn_mfma_f32_16x16x32_bf16(afr[mi], bfr[ci],
                                                                acc[mi][ci], 0, 0, 0);
      __syncthreads();
    }

    // epilogue: bias + fp16, write TRANSPOSED into LDS (tcol = d*4+hh)
#pragma unroll
    for (int mi = 0; mi < 2; ++mi)
#pragma unroll
      for (int ci = 0; ci < 4; ++ci) {
        int col = wn + ci * 16 + (lane & 15);
        int tcol = ((col & 63) << 2) | (col >> 6);
        float bv = bias[col];
#pragma unroll
        for (int r = 0; r < 4; ++r) {
          int row = mi * 16 + (lane >> 4) * 4 + r;
          Htt[row * 264 + tcol] = __half_as_ushort(__float2half(acc[mi][ci][r] + bv));
        }
      }
    __syncthreads();

    // pack fp8 h8t + outbase (self path, fp32) + fused al/eal
    int row = t >> 3, c = t & 7;   // c -> d chunk [c*8, c*8+8)
    int gr = r0 + row;
    float pa[2][4] = {{0.f, 0.f, 0.f, 0.f}, {0.f, 0.f, 0.f, 0.f}};
    if (gr < NN) {
      unsigned short pv[32];
#pragma unroll
      for (int q = 0; q < 4; ++q)
        *(uint4*)(pv + q * 8) = *(uint4*)(Htt + row * 264 + c * 32 + q * 8);
      float beta2 = beta[gr * 3 + 2] * 0.25f;
      unsigned int packed[8];
      float outb[8];
#pragma unroll
      for (int dl = 0; dl < 8; ++dl) {
        int d = c * 8 + dl;
        float f0 = __half2float(__ushort_as_half(pv[dl * 4 + 0]));
        float f1 = __half2float(__ushort_as_half(pv[dl * 4 + 1]));
        float f2 = __half2float(__ushort_as_half(pv[dl * 4 + 2]));
        float f3 = __half2float(__ushort_as_half(pv[dl * 4 + 3]));
        pa[0][0] = fmaf(f0, attn_l[0 * 64 + d], pa[0][0]);
        pa[0][1] = fmaf(f1, attn_l[1 * 64 + d], pa[0][1]);
        pa[0][2] = fmaf(f2, attn_l[2 * 64 + d], pa[0][2]);
        pa[0][3] = fmaf(f3, attn_l[3 * 64 + d], pa[0][3]);
        pa[1][0] = fmaf(f0, attn_l[256 + 0 * 64 + d], pa[1][0]);
        pa[1][1] = fmaf(f1, attn_l[256 + 1 * 64 + d], pa[1][1]);
        pa[1][2] = fmaf(f2, attn_l[256 + 2 * 64 + d], pa[1][2]);
        pa[1][3] = fmaf(f3, attn_l[256 + 3 * 64 + d], pa[1][3]);
        unsigned int pk8 = f2_to_fp8pair<false>(f0, f1, 0u);
        pk8 = f2_to_fp8pair<true>(f2, f3, pk8);
        packed[dl] = pk8;
        outb[dl] = beta2 * (f0 + f1 + f2 + f3);
      }
      unsigned int* hdst = h8t + (size_t)gr * 64 + c * 8;
      *(uint4*)hdst       = *(uint4*)&packed[0];
      *(uint4*)(hdst + 4) = *(uint4*)&packed[4];
      float* odst = outbase + (size_t)gr * 64 + c * 8;
      *(float4*)odst       = *(float4*)&outb[0];
      *(float4*)(odst + 4) = *(float4*)&outb[4];
    }
#pragma unroll
    for (int o = 1; o < 8; o <<= 1)
#pragma unroll
      for (int m2 = 0; m2 < 2; ++m2)
#pragma unroll
        for (int hh = 0; hh < 4; ++hh)
          pa[m2][hh] += __shfl_xor(pa[m2][hh], o);
    if (c == 0 && gr < NN) {
      float a0s = alpha[0], a1s = alpha[1];
      union { unsigned short s[4]; unsigned long long u; } p0, p1;
#pragma unroll
      for (int hh = 0; hh < 4; ++hh) {
        p0.s[hh] = __half_as_ushort(__float2half(__expf(a0s * pa[0][hh])));
        p1.s[hh] = __half_as_ushort(__float2half(__expf(a1s * pa[1][hh])));
      }
      eal[gr] = p0.u;
      eal[(size_t)NN + gr] = p1.u;
    }
  }
}

// ---------------- aggregate: one wave per dst; fp8 gathers, f32 weights ----------------
__global__ __launch_bounds__(256) void k_agg(const int* __restrict__ off,
                                             const int* __restrict__ rec,
                                             const unsigned long long* __restrict__ eal,
                                             const unsigned int* __restrict__ h8t,
                                             const float* __restrict__ beta,
                                             const float* __restrict__ outbase,
                                             float* __restrict__ out) {
  int lane = threadIdx.x & 63;
  int dst  = (int)((blockIdx.x * (size_t)blockDim.x + threadIdx.x) >> 6);
  if (dst >= NN) return;
  int dstu = __builtin_amdgcn_readfirstlane(dst);
  float msg = 0.f;
#pragma unroll
  for (int m = 0; m < MM; ++m) {
    int cntm = off[(size_t)m * NN + dstu];
    cntm = min(cntm, CAP);
    if (cntm <= 0) continue;
    const int* rr = rec + ((size_t)m * NN + dstu) * CAP;
    int srcl = 0;
    unsigned int el = 0, eh = 0;
    float s0 = 0.f, s1 = 0.f, s2 = 0.f, s3 = 0.f;
    if (lane < cntm) {
      srcl = rr[lane];
      unsigned long long ev = eal[(size_t)m * NN + srcl];
      el = (unsigned int)ev; eh = (unsigned int)(ev >> 32);
      float2 w01 = u32_to_f2(el), w23 = u32_to_f2(eh);
      s0 = w01.x; s1 = w01.y; s2 = w23.x; s3 = w23.y;
    }
#pragma unroll
    for (int o = 1; o < 64; o <<= 1) {
      s0 += __shfl_xor(s0, o);
      s1 += __shfl_xor(s1, o);
      s2 += __shfl_xor(s2, o);
      s3 += __shfl_xor(s3, o);
    }
    float bs = beta[dstu * 3 + m] * 0.25f;
    float c0 = bs / (s0 + 1e-16f), c1 = bs / (s1 + 1e-16f);
    float c2 = bs / (s2 + 1e-16f), c3 = bs / (s3 + 1e-16f);
    // pre-scaled per-edge weights live in lane p
    float w0 = 0.f, w1 = 0.f, w2 = 0.f, w3 = 0.f;
    if (lane < cntm) {
      float2 w01 = u32_to_f2(el), w23 = u32_to_f2(eh);
      w0 = w01.x * c0; w1 = w01.y * c1; w2 = w23.x * c2; w3 = w23.y * c3;
    }
    int p = 0;
    for (; p + 2 <= cntm; p += 2) {
      int sp0 = __shfl(srcl, p), sp1 = __shfl(srcl, p + 1);
      float qa0 = __shfl(w0, p), qa1 = __shfl(w1, p), qa2 = __shfl(w2, p), qa3 = __shfl(w3, p);
      float qb0 = __shfl(w0, p + 1), qb1 = __shfl(w1, p + 1), qb2 = __shfl(w2, p + 1), qb3 = __shfl(w3, p + 1);
      unsigned int hA = h8t[(size_t)sp0 * 64 + lane];
      unsigned int hB = h8t[(size_t)sp1 * 64 + lane];
      float2 fa01 = fp8pair_to_f2<false>(hA), fa23 = fp8pair_to_f2<true>(hA);
      float2 fb01 = fp8pair_to_f2<false>(hB), fb23 = fp8pair_to_f2<true>(hB);
      msg = fmaf(qa0, fa01.x, msg); msg = fmaf(qa1, fa01.y, msg);
      msg = fmaf(qa2, fa23.x, msg); msg = fmaf(qa3, fa23.y, msg);
      msg = fmaf(qb0, fb01.x, msg); msg = fmaf(qb1, fb01.y, msg);
      msg = fmaf(qb2, fb23.x, msg); msg = fmaf(qb3, fb23.y, msg);
    }
    if (p < cntm) {
      int sp0 = __shfl(srcl, p);
      float qa0 = __shfl(w0, p), qa1 = __shfl(w1, p), qa2 = __shfl(w2, p), qa3 = __shfl(w3, p);
      unsigned int hA = h8t[(size_t)sp0 * 64 + lane];
      float2 fa01 = fp8pair_to_f2<false>(hA), fa23 = fp8pair_to_f2<true>(hA);
      msg = fmaf(qa0, fa01.x, msg); msg = fmaf(qa1, fa01.y, msg);
      msg = fmaf(qa2, fa23.x, msg); msg = fmaf(qa3, fa23.y, msg);
    }
  }
  float v = msg + outbase[(size_t)dstu * 64 + lane];
  out[(size_t)dstu * 64 + lane] = fmaxf(v, 0.f);
}

extern "C" void kernel_launch(void* const* d_in, const int* in_sizes, int n_in,
                              void* d_out, int out_size, void* d_ws, size_t ws_size,
                              hipStream_t stream) {
  const float* x      = (const float*)d_in[0];
  const float* W      = (const float*)d_in[1];
  const float* b      = (const float*)d_in[2];
  const float* cw     = (const float*)d_in[3];
  const float* cb     = (const float*)d_in[4];
  const float* attn_l = (const float*)d_in[5];
  const float* attn_r = (const float*)d_in[6];  // unused: softmax shift-invariance cancels ar
  const float* alpha  = (const float*)d_in[7];
  const int*   e0     = (const int*)d_in[8];
  const int*   e1     = (const int*)d_in[9];
  float* out = (float*)d_out;
  (void)attn_r;

  char* p = (char*)d_ws;
  unsigned short* Wt   = (unsigned short*)p;  p += (size_t)256 * 256 * 2;        // 128 KB
  unsigned int* h8t    = (unsigned int*)p;    p += (size_t)NN * 64 * 4;          // 12.8 MB
  float* outbase = (float*)p;                 p += (size_t)NN * 64 * 4;          // 12.8 MB
  uint2* binned = (uint2*)p;                  p += (size_t)MM * NB * CAPBIN * 8; // 19.3 MB
  unsigned long long* eal = (unsigned long long*)p; p += (size_t)MM * NN * 8;    // 800 KB
  float* beta   = (float*)p;                  p += (size_t)NN * 3 * 4;           // 600 KB
  int*   off    = (int*)p;                    p += (size_t)MM * NN * 4;          // 400 KB
  int*   rec    = (int*)p;                    p += (size_t)MM * NN * CAP * 4;    // 25.6 MB
  int*   cursor = (int*)p;                    p += (size_t)MM * NB * 4;          // 1.6 KB

  hipMemsetAsync(cursor, 0, (size_t)MM * NB * 4, stream);

  int frontBlocks = PARTA_BLKS + WT_BLKS + BETA_BLKS;
  k_front<<<frontBlocks, 256, 0, stream>>>(e0, e1, cursor, binned,
                                           W, Wt, x, cw, cb, beta);

  k_gemmb<<<PARTB_BLKS + GB, 256, 0, stream>>>(cursor, binned, off, rec,
                                               x, Wt, b, attn_l, alpha, beta,
                                               h8t, outbase, eal);

  int nodeBlocks = (NN * 64 + 255) / 256;  // 12500 blocks = 50000 waves
  k_agg<<<nodeBlocks, 256, 0, stream>>>(off, rec, eal, h8t, beta, outbase, out);
}

// Round 14
// 170.283 us; speedup vs baseline: 1.6367x; 1.2883x over previous
//
#include <hip/hip_runtime.h>
#include <hip/hip_fp16.h>
#include <hip/hip_fp8.h>

#define NN 50000
#define FF 256
#define EE 1000000
#define MM 2
#define CAP 64

#define NB 196       // coarse bins: dst>>8
#define CAPBIN 6144
#define ACHUNK 4096
#define ABLK 245     // ceil(EE/ACHUNK)

typedef __attribute__((ext_vector_type(8))) short bf16x8;
typedef __attribute__((ext_vector_type(4))) float f32x4;
typedef __attribute__((ext_vector_type(2))) float f32x2;

__device__ inline unsigned short f2bf(float f) {
  union { float f; unsigned u; } v; v.f = f;
  unsigned r = (v.u + 0x7FFF + ((v.u >> 16) & 1)) >> 16;
  return (unsigned short)r;
}

__device__ inline float2 u32_to_f2(unsigned int u) {
  union { unsigned int u; __half2 h; } c; c.u = u;
  return __half22float2(c.h);
}

#if __has_builtin(__builtin_amdgcn_cvt_pk_f32_fp8) && __has_builtin(__builtin_amdgcn_cvt_pk_fp8_f32)
template <bool HI>
__device__ inline float2 fp8pair_to_f2(unsigned int u) {
  f32x2 r = __builtin_amdgcn_cvt_pk_f32_fp8((int)u, HI);
  return make_float2(r[0], r[1]);
}
template <bool HI>
__device__ inline unsigned int f2_to_fp8pair(float a, float b, unsigned int old) {
  return (unsigned int)__builtin_amdgcn_cvt_pk_fp8_f32(a, b, (int)old, HI);
}
#else
template <bool HI>
__device__ inline float2 fp8pair_to_f2(unsigned int u) {
  unsigned int w = HI ? (u >> 16) : (u & 0xFFFFu);
  __half_raw h0 = __hip_cvt_fp8_to_halfraw((__hip_fp8_storage_t)(w & 0xFF), __HIP_E4M3);
  __half_raw h1 = __hip_cvt_fp8_to_halfraw((__hip_fp8_storage_t)(w >> 8), __HIP_E4M3);
  return make_float2(__half2float(__half(h0)), __half2float(__half(h1)));
}
template <bool HI>
__device__ inline unsigned int f2_to_fp8pair(float a, float b, unsigned int old) {
  unsigned int pa = (unsigned int)__hip_cvt_float_to_fp8(a, __HIP_SATFINITE, __HIP_E4M3);
  unsigned int pb = (unsigned int)__hip_cvt_float_to_fp8(b, __HIP_SATFINITE, __HIP_E4M3);
  unsigned int w = pa | (pb << 8);
  return HI ? ((old & 0x0000FFFFu) | (w << 16)) : ((old & 0xFFFF0000u) | w);
}
#endif

// ---------------- fused front: edge coarse-binning | Wt cast | beta ----------------
#define PARTA_BLKS (2 * ABLK)   // 490
#define WT_BLKS 256
#define BETA_BLKS 12500
__global__ __launch_bounds__(256) void k_front(const int* __restrict__ e0,
                                               const int* __restrict__ e1,
                                               int* __restrict__ cursor,
                                               uint2* __restrict__ binned,
                                               const float* __restrict__ W,
                                               unsigned short* __restrict__ Wt,
                                               const float* __restrict__ x,
                                               const float* __restrict__ cw,
                                               const float* __restrict__ cb,
                                               float* __restrict__ beta) {
  __shared__ int lsrc[ACHUNK];
  __shared__ int ldst[ACHUNK];
  __shared__ int cnt[NB], base[NB], pos[NB];
  int b = blockIdx.x;
  int tid = threadIdx.x;
  if (b < PARTA_BLKS) {
    int m = (b >= ABLK) ? 1 : 0;
    int ab = b - m * ABLK;
    const int* e = m ? e1 : e0;
    int j0 = ab * ACHUNK;
    int nj = min(ACHUNK, EE - j0);
    if (tid < NB) { cnt[tid] = 0; pos[tid] = 0; }
    __syncthreads();
    for (int i = tid; i < nj; i += 256) {
      int s = e[j0 + i], d = e[EE + j0 + i];
      lsrc[i] = s; ldst[i] = d;
      atomicAdd(&cnt[d >> 8], 1);
    }
    __syncthreads();
    if (tid < NB) {
      base[tid] = (cnt[tid] > 0) ? atomicAdd(&cursor[m * NB + tid], cnt[tid]) : 0;
    }
    __syncthreads();
    for (int i = tid; i < nj; i += 256) {
      int d = ldst[i], bin = d >> 8;
      int lp = atomicAdd(&pos[bin], 1);
      int slot = base[bin] + lp;
      if (slot < CAPBIN)
        binned[((size_t)m * NB + bin) * CAPBIN + slot] =
            make_uint2((unsigned)lsrc[i], (unsigned)d);
    }
    return;
  }
  b -= PARTA_BLKS;
  if (b < WT_BLKS) {
    Wt[b * 256 + tid] = f2bf(W[tid * 256 + b]);
    return;
  }
  b -= WT_BLKS;
  {
    int wid  = b * 4 + (tid >> 6);
    int lane = tid & 63;
    float4 xv = *reinterpret_cast<const float4*>(x + (size_t)wid * FF + lane * 4);
    float s[3];
#pragma unroll
    for (int r = 0; r < 3; ++r) {
      float4 wv = *reinterpret_cast<const float4*>(cw + r * FF + lane * 4);
      float p = xv.x * wv.x + xv.y * wv.y + xv.z * wv.z + xv.w * wv.w;
#pragma unroll
      for (int o = 1; o < 64; o <<= 1) p += __shfl_xor(p, o);
      s[r] = p + cb[r];
    }
    float mx = fmaxf(s[0], fmaxf(s[1], s[2]));
    float e0v = expf(s[0] - mx), e1v = expf(s[1] - mx), e2v = expf(s[2] - mx);
    float inv = 1.f / (e0v + e1v + e2v);
    if (lane == 0) {
      beta[wid * 3 + 0] = e0v * inv;
      beta[wid * 3 + 1] = e1v * inv;
      beta[wid * 3 + 2] = e2v * inv;
    }
  }
}

// ---------------- fused: partb | MFMA GEMM -> h8t (fp8, transposed) + eal + outbase ----------------
#define PARTB_BLKS (2 * NB)          // 392
#define GB 1563                       // ceil(NN/32)
__global__ __launch_bounds__(256) void k_gemmb(const int* __restrict__ cursor,
                                               const uint2* __restrict__ binned,
                                               int* __restrict__ off,
                                               int* __restrict__ rec,
                                               const float* __restrict__ x,
                                               const unsigned short* __restrict__ Wt,
                                               const float* __restrict__ bias,
                                               const float* __restrict__ attn_l,
                                               const float* __restrict__ alpha,
                                               const float* __restrict__ beta,
                                               unsigned int* __restrict__ h8t,
                                               float* __restrict__ outbase,
                                               unsigned long long* __restrict__ eal) {
  __shared__ __attribute__((aligned(16))) char smem[(32 * 264 + 256 * 40) * 2];
  int b = blockIdx.x;
  int t = threadIdx.x;

  if (b < PARTB_BLKS) {
    int* cnt = (int*)smem;
    int* pos = cnt + 256;
    int m = (b >= NB) ? 1 : 0;
    int bin = b - m * NB;
    int n = min(cursor[m * NB + bin], CAPBIN);
    cnt[t] = 0; pos[t] = 0;
    __syncthreads();
    const uint2* seg = binned + ((size_t)m * NB + bin) * CAPBIN;
    for (int i = t; i < n; i += 256) atomicAdd(&cnt[seg[i].y & 255], 1);
    __syncthreads();
    int dg = bin * 256 + t;
    if (dg < NN) off[(size_t)m * NN + dg] = min(cnt[t], CAP);
    for (int i = t; i < n; i += 256) {
      uint2 r = seg[i];
      int dl = (int)(r.y & 255u);
      int lp = atomicAdd(&pos[dl], 1);
      if (lp < CAP) rec[((size_t)m * NN + r.y) * CAP + lp] = (int)r.x;
    }
    return;
  }
  b -= PARTB_BLKS;
  {
    unsigned short* As = (unsigned short*)smem;            // [32][264]
    unsigned short* Bs = As + 32 * 264;                    // [256][40]
    unsigned short* Htt = Bs;                              // reuse after K-loop: [32][264]
    const int lane = t & 63, w = t >> 6;
    const int wn = w * 64;
    const int r0 = b * 32;
    const int arow = lane & 15, kg = (lane >> 4) * 8;

    // stage A fully (32 rows x 256 k) from fp32 x, cast to bf16
    {
      int row = t >> 3, kc = (t & 7) * 32;
      int gr = r0 + row; if (gr >= NN) gr = NN - 1;
      const float* sp = x + (size_t)gr * FF + kc;
      unsigned short* dp = As + row * 264 + kc;
#pragma unroll
      for (int q = 0; q < 8; ++q) {
        float4 f = *(const float4*)(sp + q * 4);
        unsigned short u[4] = {f2bf(f.x), f2bf(f.y), f2bf(f.z), f2bf(f.w)};
        *(uint2*)(dp + q * 4) = *(uint2*)u;
      }
    }

    f32x4 acc[2][4] = {};
    for (int k0 = 0; k0 < FF; k0 += 32) {
#pragma unroll
      for (int s = 0; s < 4; ++s) {
        int i = t + 256 * s;
        int n2 = i >> 2, ch = (i & 3) * 8;
        *(uint4*)(Bs + n2 * 40 + ch) = *(const uint4*)(Wt + (size_t)n2 * FF + k0 + ch);
      }
      __syncthreads();
      bf16x8 afr[2], bfr[4];
      afr[0] = *(bf16x8*)(As + arow * 264 + k0 + kg);
      afr[1] = *(bf16x8*)(As + (16 + arow) * 264 + k0 + kg);
#pragma unroll
      for (int ci = 0; ci < 4; ++ci)
        bfr[ci] = *(bf16x8*)(Bs + (wn + ci * 16 + arow) * 40 + kg);
#pragma unroll
      for (int mi = 0; mi < 2; ++mi)
#pragma unroll
        for (int ci = 0; ci < 4; ++ci)
          acc[mi][ci] = __builtin_amdgcn_mfma_f32_16x16x32_bf16(afr[mi], bfr[ci],
                                                                acc[mi][ci], 0, 0, 0);
      __syncthreads();
    }

    // epilogue: bias + fp16, write TRANSPOSED into LDS (tcol = d*4+hh)
#pragma unroll
    for (int mi = 0; mi < 2; ++mi)
#pragma unroll
      for (int ci = 0; ci < 4; ++ci) {
        int col = wn + ci * 16 + (lane & 15);
        int tcol = ((col & 63) << 2) | (col >> 6);
        float bv = bias[col];
#pragma unroll
        for (int r = 0; r < 4; ++r) {
          int row = mi * 16 + (lane >> 4) * 4 + r;
          Htt[row * 264 + tcol] = __half_as_ushort(__float2half(acc[mi][ci][r] + bv));
        }
      }
    __syncthreads();

    // pack fp8 h8t + outbase (self path, fp32) + fused al/eal
    int row = t >> 3, c = t & 7;   // c -> d chunk [c*8, c*8+8)
    int gr = r0 + row;
    float pa[2][4] = {{0.f, 0.f, 0.f, 0.f}, {0.f, 0.f, 0.f, 0.f}};
    if (gr < NN) {
      unsigned short pv[32];
#pragma unroll
      for (int q = 0; q < 4; ++q)
        *(uint4*)(pv + q * 8) = *(uint4*)(Htt + row * 264 + c * 32 + q * 8);
      float beta2 = beta[gr * 3 + 2] * 0.25f;
      unsigned int packed[8];
      float outb[8];
#pragma unroll
      for (int dl = 0; dl < 8; ++dl) {
        int d = c * 8 + dl;
        float f0 = __half2float(__ushort_as_half(pv[dl * 4 + 0]));
        float f1 = __half2float(__ushort_as_half(pv[dl * 4 + 1]));
        float f2 = __half2float(__ushort_as_half(pv[dl * 4 + 2]));
        float f3 = __half2float(__ushort_as_half(pv[dl * 4 + 3]));
        pa[0][0] = fmaf(f0, attn_l[0 * 64 + d], pa[0][0]);
        pa[0][1] = fmaf(f1, attn_l[1 * 64 + d], pa[0][1]);
        pa[0][2] = fmaf(f2, attn_l[2 * 64 + d], pa[0][2]);
        pa[0][3] = fmaf(f3, attn_l[3 * 64 + d], pa[0][3]);
        pa[1][0] = fmaf(f0, attn_l[256 + 0 * 64 + d], pa[1][0]);
        pa[1][1] = fmaf(f1, attn_l[256 + 1 * 64 + d], pa[1][1]);
        pa[1][2] = fmaf(f2, attn_l[256 + 2 * 64 + d], pa[1][2]);
        pa[1][3] = fmaf(f3, attn_l[256 + 3 * 64 + d], pa[1][3]);
        unsigned int pk8 = f2_to_fp8pair<false>(f0, f1, 0u);
        pk8 = f2_to_fp8pair<true>(f2, f3, pk8);
        packed[dl] = pk8;
        outb[dl] = beta2 * (f0 + f1 + f2 + f3);
      }
      unsigned int* hdst = h8t + (size_t)gr * 64 + c * 8;
      *(uint4*)hdst       = *(uint4*)&packed[0];
      *(uint4*)(hdst + 4) = *(uint4*)&packed[4];
      float* odst = outbase + (size_t)gr * 64 + c * 8;
      *(float4*)odst       = *(float4*)&outb[0];
      *(float4*)(odst + 4) = *(float4*)&outb[4];
    }
#pragma unroll
    for (int o = 1; o < 8; o <<= 1)
#pragma unroll
      for (int m2 = 0; m2 < 2; ++m2)
#pragma unroll
        for (int hh = 0; hh < 4; ++hh)
          pa[m2][hh] += __shfl_xor(pa[m2][hh], o);
    if (c == 0 && gr < NN) {
      float a0s = alpha[0], a1s = alpha[1];
      union { unsigned short s[4]; unsigned long long u; } p0, p1;
#pragma unroll
      for (int hh = 0; hh < 4; ++hh) {
        p0.s[hh] = __half_as_ushort(__float2half(__expf(a0s * pa[0][hh])));
        p1.s[hh] = __half_as_ushort(__float2half(__expf(a1s * pa[1][hh])));
      }
      eal[gr] = p0.u;
      eal[(size_t)NN + gr] = p1.u;
    }
  }
}

// ---------------- aggregate: one wave per dst; half-wave edge pairing, deep MLP ----------------
// lanes 0-31 process even edges, 32-63 odd edges; each lane covers 2 d-values (uint2 row chunk)
__global__ __launch_bounds__(256) void k_agg(const int* __restrict__ off,
                                             const int* __restrict__ rec,
                                             const unsigned long long* __restrict__ eal,
                                             const uint2* __restrict__ h8,
                                             const float* __restrict__ beta,
                                             const float* __restrict__ outbase,
                                             float* __restrict__ out) {
  int lane = threadIdx.x & 63;
  int half = lane >> 5;
  int lh   = lane & 31;
  int dst  = (int)((blockIdx.x * (size_t)blockDim.x + threadIdx.x) >> 6);
  if (dst >= NN) return;
  int dstu = __builtin_amdgcn_readfirstlane(dst);
  float msg0 = 0.f, msg1 = 0.f;   // d = 2*lh, 2*lh+1
#pragma unroll
  for (int m = 0; m < MM; ++m) {
    int cntm = off[(size_t)m * NN + dstu];
    cntm = min(cntm, CAP);
    if (cntm <= 0) continue;
    const int* rr = rec + ((size_t)m * NN + dstu) * CAP;
    int srcl = 0;
    unsigned int el = 0, eh = 0;
    float s0 = 0.f, s1 = 0.f, s2 = 0.f, s3 = 0.f;
    if (lane < cntm) {
      srcl = rr[lane];
      unsigned long long ev = eal[(size_t)m * NN + srcl];
      el = (unsigned int)ev; eh = (unsigned int)(ev >> 32);
      float2 w01 = u32_to_f2(el), w23 = u32_to_f2(eh);
      s0 = w01.x; s1 = w01.y; s2 = w23.x; s3 = w23.y;
    }
#pragma unroll
    for (int o = 1; o < 64; o <<= 1) {
      s0 += __shfl_xor(s0, o);
      s1 += __shfl_xor(s1, o);
      s2 += __shfl_xor(s2, o);
      s3 += __shfl_xor(s3, o);
    }
    float bs = beta[dstu * 3 + m] * 0.25f;
    float c0 = bs / (s0 + 1e-16f), c1 = bs / (s1 + 1e-16f);
    float c2 = bs / (s2 + 1e-16f), c3 = bs / (s3 + 1e-16f);
    float w0 = 0.f, w1 = 0.f, w2 = 0.f, w3 = 0.f;
    if (lane < cntm) {
      float2 w01 = u32_to_f2(el), w23 = u32_to_f2(eh);
      w0 = w01.x * c0; w1 = w01.y * c1; w2 = w23.x * c2; w3 = w23.y * c3;
    }
    int p = 0;
    // main: 4 pairs (8 edges) per iteration, loads batched for MLP
    for (; p + 8 <= cntm; p += 8) {
      int se[4];
#pragma unroll
      for (int q = 0; q < 4; ++q) se[q] = __shfl(srcl, p + 2 * q + half);
      uint2 hv[4];
#pragma unroll
      for (int q = 0; q < 4; ++q) hv[q] = h8[(size_t)se[q] * 32 + lh];
#pragma unroll
      for (int q = 0; q < 4; ++q) {
        int sel = p + 2 * q + half;
        float q0 = __shfl(w0, sel), q1 = __shfl(w1, sel);
        float q2 = __shfl(w2, sel), q3 = __shfl(w3, sel);
        float2 a01 = fp8pair_to_f2<false>(hv[q].x), a23 = fp8pair_to_f2<true>(hv[q].x);
        float2 b01 = fp8pair_to_f2<false>(hv[q].y), b23 = fp8pair_to_f2<true>(hv[q].y);
        msg0 = fmaf(q0, a01.x, msg0); msg0 = fmaf(q1, a01.y, msg0);
        msg0 = fmaf(q2, a23.x, msg0); msg0 = fmaf(q3, a23.y, msg0);
        msg1 = fmaf(q0, b01.x, msg1); msg1 = fmaf(q1, b01.y, msg1);
        msg1 = fmaf(q2, b23.x, msg1); msg1 = fmaf(q3, b23.y, msg1);
      }
    }
    // remainder: masked pairs
    for (; p < cntm; p += 2) {
      int idx = p + half;
      bool valid = idx < cntm;
      int sel = valid ? idx : (cntm - 1);
      int se = __shfl(srcl, sel);
      uint2 hv = h8[(size_t)se * 32 + lh];
      float q0 = __shfl(w0, sel), q1 = __shfl(w1, sel);
      float q2 = __shfl(w2, sel), q3 = __shfl(w3, sel);
      if (!valid) { q0 = q1 = q2 = q3 = 0.f; }
      float2 a01 = fp8pair_to_f2<false>(hv.x), a23 = fp8pair_to_f2<true>(hv.x);
      float2 b01 = fp8pair_to_f2<false>(hv.y), b23 = fp8pair_to_f2<true>(hv.y);
      msg0 = fmaf(q0, a01.x, msg0); msg0 = fmaf(q1, a01.y, msg0);
      msg0 = fmaf(q2, a23.x, msg0); msg0 = fmaf(q3, a23.y, msg0);
      msg1 = fmaf(q0, b01.x, msg1); msg1 = fmaf(q1, b01.y, msg1);
      msg1 = fmaf(q2, b23.x, msg1); msg1 = fmaf(q3, b23.y, msg1);
    }
  }
  // combine halves (both halves end up with the full sum)
  msg0 += __shfl_xor(msg0, 32);
  msg1 += __shfl_xor(msg1, 32);
  if (half == 0) {
    float2 ob = *reinterpret_cast<const float2*>(outbase + (size_t)dstu * 64 + lh * 2);
    float v0 = msg0 + ob.x, v1 = msg1 + ob.y;
    *reinterpret_cast<float2*>(out + (size_t)dstu * 64 + lh * 2) =
        make_float2(fmaxf(v0, 0.f), fmaxf(v1, 0.f));
  }
}

extern "C" void kernel_launch(void* const* d_in, const int* in_sizes, int n_in,
                              void* d_out, int out_size, void* d_ws, size_t ws_size,
                              hipStream_t stream) {
  const float* x      = (const float*)d_in[0];
  const float* W      = (const float*)d_in[1];
  const float* b      = (const float*)d_in[2];
  const float* cw     = (const float*)d_in[3];
  const float* cb     = (const float*)d_in[4];
  const float* attn_l = (const float*)d_in[5];
  const float* attn_r = (const float*)d_in[6];  // unused: softmax shift-invariance cancels ar
  const float* alpha  = (const float*)d_in[7];
  const int*   e0     = (const int*)d_in[8];
  const int*   e1     = (const int*)d_in[9];
  float* out = (float*)d_out;
  (void)attn_r;

  char* p = (char*)d_ws;
  unsigned short* Wt   = (unsigned short*)p;  p += (size_t)256 * 256 * 2;        // 128 KB
  unsigned int* h8t    = (unsigned int*)p;    p += (size_t)NN * 64 * 4;          // 12.8 MB
  float* outbase = (float*)p;                 p += (size_t)NN * 64 * 4;          // 12.8 MB
  uint2* binned = (uint2*)p;                  p += (size_t)MM * NB * CAPBIN * 8; // 19.3 MB
  unsigned long long* eal = (unsigned long long*)p; p += (size_t)MM * NN * 8;    // 800 KB
  float* beta   = (float*)p;                  p += (size_t)NN * 3 * 4;           // 600 KB
  int*   off    = (int*)p;                    p += (size_t)MM * NN * 4;          // 400 KB
  int*   rec    = (int*)p;                    p += (size_t)MM * NN * CAP * 4;    // 25.6 MB
  int*   cursor = (int*)p;                    p += (size_t)MM * NB * 4;          // 1.6 KB

  hipMemsetAsync(cursor, 0, (size_t)MM * NB * 4, stream);

  int frontBlocks = PARTA_BLKS + WT_BLKS + BETA_BLKS;
  k_front<<<frontBlocks, 256, 0, stream>>>(e0, e1, cursor, binned,
                                           W, Wt, x, cw, cb, beta);

  k_gemmb<<<PARTB_BLKS + GB, 256, 0, stream>>>(cursor, binned, off, rec,
                                               x, Wt, b, attn_l, alpha, beta,
                                               h8t, outbase, eal);

  int nodeBlocks = (NN * 64 + 255) / 256;  // 12500 blocks = 50000 waves
  k_agg<<<nodeBlocks, 256, 0, stream>>>(off, rec, eal, (const uint2*)h8t, beta, outbase, out);
}